// Round 9
// baseline (210.195 us; speedup 1.0000x reference)
//
#include <hip/hip_runtime.h>
#include <hip/hip_bf16.h>
#include <stdint.h>

using bf16 = __hip_bfloat16;
typedef __attribute__((ext_vector_type(4))) short shorts4;
typedef __attribute__((ext_vector_type(8))) short short8;
typedef __attribute__((ext_vector_type(4))) float floatx4;
typedef __attribute__((ext_vector_type(16))) float floatx16;
typedef __attribute__((ext_vector_type(4))) unsigned int uintx4;

constexpr int BATCH = 2;
constexpr int SEQ   = 2048;
constexpr int NH    = 16;
constexpr int DH    = 64;
constexpr int DM    = 1024;
constexpr int MROWS = BATCH * SEQ;        // 4096
constexpr int OUTN  = MROWS * DM;         // 4194304
constexpr int WN    = DM * DM;            // 1048576

__device__ inline short bfbits(float x) {
    bf16 h = __float2bfloat16(x);
    return __builtin_bit_cast(short, h);
}

__device__ inline unsigned pack2(float a, float b) {
    return (unsigned)(unsigned short)bfbits(a) |
           ((unsigned)(unsigned short)bfbits(b) << 16);
}

// async global->LDS, 16B per lane (m97 pattern; dest = wave base + lane*16)
__device__ inline void async16(bf16* lds, const bf16* g) {
    __builtin_amdgcn_global_load_lds(
        (const __attribute__((address_space(1))) unsigned int*)g,
        (__attribute__((address_space(3))) unsigned int*)lds, 16, 0, 0);
}

__device__ inline void cvt8(const float* src, bf16* dst) {
    float4 f0 = *(const float4*)(src);
    float4 f1 = *(const float4*)(src + 4);
    short8 o;
    o[0] = bfbits(f0.x); o[1] = bfbits(f0.y); o[2] = bfbits(f0.z); o[3] = bfbits(f0.w);
    o[4] = bfbits(f1.x); o[5] = bfbits(f1.y); o[6] = bfbits(f1.z); o[7] = bfbits(f1.w);
    *(short8*)(dst) = o;
}

// ============ fp32 -> bf16 pre-convert (merged: all 5 tensors, 1 dispatch) ============
__global__ __launch_bounds__(256)
void cvt_all(const float* __restrict__ x,  const float* __restrict__ wq,
             const float* __restrict__ wk, const float* __restrict__ wv,
             const float* __restrict__ wo, bf16* __restrict__ dst,
             bf16* __restrict__ wob)
{
    const size_t i = ((size_t)blockIdx.x * 256 + threadIdx.x) * 8;
    if (i < (size_t)OUTN + 3 * WN) {
        const float* src; size_t off;
        if (i < (size_t)OUTN)               { src = x;  off = i; }
        else if (i < (size_t)OUTN + WN)     { src = wq; off = i - OUTN; }
        else if (i < (size_t)OUTN + 2 * WN) { src = wk; off = i - OUTN - WN; }
        else                                { src = wv; off = i - OUTN - 2 * (size_t)WN; }
        cvt8(src + off, dst + i);
    } else {
        const size_t off = i - OUTN - 3 * (size_t)WN;
        cvt8(wo + off, wob + off);
    }
}

// fallback path kernels (ws < 26 MB)
__global__ __launch_bounds__(256)
void cvt_inputs(const float* __restrict__ x,  const float* __restrict__ wq,
                const float* __restrict__ wk, const float* __restrict__ wv,
                bf16* __restrict__ dst)
{
    const size_t i = ((size_t)blockIdx.x * 256 + threadIdx.x) * 8;
    const float* src; size_t off;
    if (i < (size_t)OUTN)               { src = x;  off = i; }
    else if (i < (size_t)OUTN + WN)     { src = wq; off = i - OUTN; }
    else if (i < (size_t)OUTN + 2 * WN) { src = wk; off = i - OUTN - WN; }
    else                                { src = wv; off = i - OUTN - 2 * (size_t)WN; }
    cvt8(src + off, dst + i);
}

__global__ __launch_bounds__(256)
void cvt_wo(const float* __restrict__ wo, bf16* __restrict__ dst)
{
    const size_t i = ((size_t)blockIdx.x * 256 + threadIdx.x) * 8;
    cvt8(wo + i, dst + i);
}

// ============ bf16 MFMA GEMM, fused-z, 512 thr, BK=64 dbuf 2ph (R4-verified) ============
// MODE 0 (NZ=3): A=xb; z0 -> q PRESCALED, z1 -> k, z2 -> V^T packed stores.
// MODE 1 (NZ=1): A=attn-out; output fp32 row-major.
template<int MODE, int NZ>
__global__ __launch_bounds__(512, 2)
void gemm_mfma(const bf16* __restrict__ A,
               const bf16* __restrict__ W0, const bf16* __restrict__ W1,
               const bf16* __restrict__ W2,
               bf16* __restrict__ C0, bf16* __restrict__ C1, bf16* __restrict__ C2,
               float* __restrict__ F)
{
    __shared__ __align__(16) bf16 smem[(1 + NZ) * 8192 * 2];

    const int t    = threadIdx.x;
    const int wave = t >> 6;
    const int lane = t & 63;
    const int quad = lane >> 4;
    const int l16  = lane & 15;
    const int m0 = blockIdx.y * 128;
    const int n0 = blockIdx.x * 128;
    const int wr = (wave >> 2) * 64;     // 2 row-groups
    const int wc = (wave & 3) * 32;      // 4 col-groups

    const bf16* Wp[3] = {W0, W1, W2};

    floatx4 acc[NZ][4][2] = {};

    auto stage = [&](int kt, int bb) {
        bf16* Bb = smem + bb * (1 + NZ) * 8192;
        const int k0 = kt * 64;
        #pragma unroll
        for (int p = 0; p < 2; p++) {
            const int ck = p * 512 + t;            // 1024 chunks per tensor
            const int kr = ck >> 3;
            const int kg = (ck & 7) ^ (kr & 7);
            async16(Bb + ck * 8, A + (size_t)(m0 + kr) * DM + k0 + kg * 8);
            #pragma unroll
            for (int zz = 0; zz < NZ; zz++)
                async16(Bb + (1 + zz) * 8192 + ck * 8,
                        Wp[zz] + (size_t)(n0 + kr) * DM + k0 + kg * 8);
        }
    };

    stage(0, 0);
    __syncthreads();                       // prologue drain: tile 0 resident

    for (int kt = 0; kt < DM / 64; ++kt) {
        const int cur = kt & 1;
        if (kt + 1 < DM / 64) stage(kt + 1, cur ^ 1);   // prefetch BEFORE compute

        const bf16* Bb = smem + cur * (1 + NZ) * 8192;

        #pragma unroll
        for (int ks = 0; ks < 2; ks++) {
            short8 af[4];
            #pragma unroll
            for (int i = 0; i < 4; i++) {
                const int r = wr + i * 16 + l16;
                af[i] = *(const short8*)(Bb + r * 64 + ((ks * 4 + quad) ^ (r & 7)) * 8);
            }
            #pragma unroll
            for (int zz = 0; zz < NZ; zz++) {
                short8 wf[2];
                #pragma unroll
                for (int j = 0; j < 2; j++) {
                    const int n = wc + j * 16 + l16;
                    wf[j] = *(const short8*)(Bb + (1 + zz) * 8192 + n * 64 +
                                             ((ks * 4 + quad) ^ (n & 7)) * 8);
                }
                __builtin_amdgcn_s_setprio(1);
                #pragma unroll
                for (int i = 0; i < 4; i++)
                    #pragma unroll
                    for (int j = 0; j < 2; j++)
                        acc[zz][i][j] = __builtin_amdgcn_mfma_f32_16x16x32_bf16(
                            af[i], wf[j], acc[zz][i][j], 0, 0, 0);
                __builtin_amdgcn_s_setprio(0);
            }
        }
        __syncthreads();   // all waves done with cur; prefetched tile resident
    }

    // ---- epilogue (C/D layout: col=lane&15, row=quad*4+reg [m89/m91]) ----
    #pragma unroll
    for (int zz = 0; zz < NZ; zz++) {
        #pragma unroll
        for (int i = 0; i < 4; i++) {
            #pragma unroll
            for (int j = 0; j < 2; j++) {
                if (MODE == 0 && zz == 2) {
                    // V^T [B,H,DH,S]: r <-> consecutive s -> packed 8B store
                    const int s0 = m0 + wr + i * 16 + quad * 4;
                    const int gn = n0 + wc + j * 16 + l16;
                    const int b = s0 >> 11, sr = s0 & (SEQ - 1);
                    const int h = gn >> 6,  d = gn & (DH - 1);
                    shorts4 pv;
                    #pragma unroll
                    for (int r = 0; r < 4; r++) pv[r] = bfbits(acc[zz][i][j][r]);
                    *(shorts4*)(C2 + (((size_t)(b * NH + h)) * DH + d) * SEQ + sr) = pv;
                } else {
                    #pragma unroll
                    for (int r = 0; r < 4; r++) {
                        const int gm = m0 + wr + i * 16 + quad * 4 + r;
                        const int gn = n0 + wc + j * 16 + l16;
                        if (MODE == 1) {
                            F[(size_t)gm * DM + gn] = acc[zz][i][j][r];    // fp32
                        } else {
                            float av = acc[zz][i][j][r];
                            if (zz == 0) av *= 0.18033688f;  // (1/sqrt(DH))*log2(e)
                            bf16* dst = (zz == 0) ? C0 : C1;
                            dst[(size_t)gm * DM + gn] = __float2bfloat16(av);
                        }
                    }
                }
            }
        }
    }
}

// ============ attn single-kt compute: one 32-key block vs one 32-q subtile ============
__device__ __forceinline__ void attn_kt(const bf16* Ks, int kb, int qrow,
                                        const short8 (&qf)[4],
                                        floatx16 (&oacc)[2], float& lsum,
                                        int kq, int hi, int l32)
{
    if (kb > qrow + 31) return;
    const bf16* Vs = Ks + 8192;
    const int qg = qrow + l32;
    const int krow = kq * 32 + l32;        // key row within the 128-key slot

    // ---- QK^T: S^T[32 keys][32 q] ----
    floatx16 sc = {};
    #pragma unroll
    for (int sg = 0; sg < 4; sg++) {
        const int g = (sg * 2 + hi) ^ (krow & 7);
        short8 kf = *(const short8*)(Ks + krow * 64 + g * 8);
        sc = __builtin_amdgcn_mfma_f32_32x32x16_bf16(kf, qf[sg], sc, 0, 0, 0);
    }

    // ---- causal mask on diagonal tiles ----
    if (kb + 31 > qrow) {
        #pragma unroll
        for (int r = 0; r < 16; r++) {
            const int key = kb + (r & 3) + 8 * (r >> 2) + 4 * hi;
            sc[r] = (key <= qg) ? sc[r] : -1e30f;
        }
    }

    // ---- p = exp2(s), partial l ----
    #pragma unroll
    for (int r = 0; r < 16; r++) {
        const float p = __builtin_amdgcn_exp2f(sc[r]);
        sc[r] = p;
        lsum += p;
    }

    // ---- pack P pairs: d[g][i] = keys 8g+4hi+2i+{0,1} (q = l32) ----
    unsigned d[4][2];
    #pragma unroll
    for (int g = 0; g < 4; g++) {
        d[g][0] = pack2(sc[4 * g + 0], sc[4 * g + 1]);
        d[g][1] = pack2(sc[4 * g + 2], sc[4 * g + 3]);
    }

    // ---- PV per 16-key segment: one shfl_xor(32) pair builds B-frag ----
    #pragma unroll
    for (int h16 = 0; h16 < 2; h16++) {
        const unsigned a0 = d[h16 * 2][0],     a1 = d[h16 * 2][1];
        const unsigned b0 = d[h16 * 2 + 1][0], b1 = d[h16 * 2 + 1][1];
        const unsigned mine0 = hi ? b0 : a0, mine1 = hi ? b1 : a1;
        const unsigned give0 = hi ? a0 : b0, give1 = hi ? a1 : b1;
        const unsigned r0 = (unsigned)__shfl_xor((int)give0, 32, 64);
        const unsigned r1 = (unsigned)__shfl_xor((int)give1, 32, 64);
        uintx4 pw;
        pw[0] = hi ? r0 : mine0;
        pw[1] = hi ? r1 : mine1;
        pw[2] = hi ? mine0 : r0;
        pw[3] = hi ? mine1 : r1;
        short8 pb = __builtin_bit_cast(short8, pw);

        const int Gbase = kq * 4 + h16 * 2 + hi;
        #pragma unroll
        for (int tile = 0; tile < 2; tile++) {
            const int vrow = tile * 32 + l32;
            const int vg = Gbase ^ (vrow & 15);
            short8 vf = *(const short8*)(Vs + vrow * 128 + vg * 8);
            oacc[tile] = __builtin_amdgcn_mfma_f32_32x32x16_bf16(vf, pb, oacc[tile], 0, 0, 0);
        }
    }
}

// ============ MFMA causal flash attention: 16-wave key-quarter split ============
// grid (8, NH, BATCH) = 256 blocks (1/CU), 1024 thr = 16 waves = 4 waves/SIMD.
// Roles: qw = wave&3 (32-row q-subtile), kq = wave>>2 (32-key quarter of each
// 128-key slot). Per wave per slot = ONE kt (half the R8 serial chain), and
// 2x the TLP (R8 ran 2 waves/SIMD) -> latency-bound stalls halve twice over.
// XCD-pinned role remap (R8): all 8 q-pair blocks of one (h,b) share id%8 ->
// same XCD -> head's K/V L2-resident. Causal-complementary pair (qtA,15-qtA)
// -> 17 uniform slots. Tri-buffered staging, counted s_waitcnt vmcnt(2).
// Epilogue: 4-round LDS combine of kq partials, then kq0 transpose-slab store.
// Q,K row-major [B,S,DM] (q prescaled by 0.125*log2e); V^T [B,H,DH,S].
// 32x32 layouts (m74/m101): C/D col=lane&31, row=(r&3)+8*(r>>2)+4*(lane>>5).
__global__ __launch_bounds__(1024, 4)
void attn_flash(bf16* __restrict__ Q, const bf16* __restrict__ K,
                const bf16* __restrict__ Vt)
{
    // 96KB: 3 x (Ks[128][64] g^=row&7 | Vs[64][128] g^=row&15) stage buffers.
    // Epilogue reuse: dmp [4qw][3kq][32][34] f32 (52KB) | lP [2][4][4][32] f32
    // | slabs bf16 @28672 (4 x 32x72).
    __shared__ __align__(16) bf16 smem[49152];

    const int t    = threadIdx.x;
    const int wave = t >> 6;
    const int lane = t & 63;
    const int hi   = lane >> 5;
    const int l32  = lane & 31;

    // ---- XCD-pinned role remap (bijective on 256 blocks) ----
    const int id  = blockIdx.x + 8 * (blockIdx.y + NH * blockIdx.z);
    const int xcd = id & 7;
    const int jj  = id >> 3;               // 0..31
    const int p   = xcd * 4 + (jj >> 3);   // head-pair index 0..31
    const int h   = p & (NH - 1);
    const int b   = p >> 4;
    const int qtA = jj & 7;                // 0..7
    const int qtB = 15 - qtA;              // 8..15

    const int hc  = h * DH;
    const size_t rowb = (size_t)b * SEQ;
    const size_t bhv  = ((size_t)(b * NH + h)) * SEQ * DH;

    const int qw = wave & 3;               // q-subtile
    const int kq = wave >> 2;              // key quarter (0..3)
    const int qrA = qtA * 128 + qw * 32;
    const int qrB = qtB * 128 + qw * 32;

    short8 qfA[4], qfB[4];
    #pragma unroll
    for (int sg = 0; sg < 4; sg++) {
        qfA[sg] = *(const short8*)(Q + (rowb + qrA + l32) * DM + hc + sg * 16 + hi * 8);
        qfB[sg] = *(const short8*)(Q + (rowb + qrB + l32) * DM + hc + sg * 16 + hi * 8);
    }

    floatx16 oaccA[2] = {}, oaccB[2] = {};
    float lsumA = 0.f, lsumB = 0.f;

    constexpr int NSLOT = 17;

    auto slotK0 = [&](int s) { return (s <= qtA ? s : s - qtA - 1) * 128; };

    // staging: 2048 16B chunks (Ks 1024 + Vs 1024), 1024 thr x 2
    auto stage = [&](int s) {
        bf16* Kb = smem + (s % 3) * 16384;
        bf16* Vb = Kb + 8192;
        const int k0 = slotK0(s);
        const int kr = t >> 3;
        const int kg = (t & 7) ^ (kr & 7);
        async16(Kb + t * 8, K + (rowb + k0 + kr) * DM + hc + kg * 8);
        const int vr = t >> 4;
        const int vg = (t & 15) ^ (vr & 15);
        async16(Vb + t * 8, Vt + bhv + (size_t)vr * SEQ + k0 + vg * 8);
    };

    // ---- pipelined main loop: issue s+2, wait slot s (vmcnt 2), compute s ----
    stage(0);
    stage(1);
    for (int s = 0; s < NSLOT - 1; ++s) {
        asm volatile("s_waitcnt vmcnt(2)" ::: "memory");   // slot s resident (own 2)
        __builtin_amdgcn_s_barrier();                      // all lanes' slot s done
        if (s + 2 < NSLOT) stage(s + 2);
        const bf16* Ks = smem + (s % 3) * 16384;
        if (s <= qtA)
            attn_kt(Ks, s * 128 + kq * 32, qrA, qfA, oaccA, lsumA, kq, hi, l32);
        else
            attn_kt(Ks, (s - qtA - 1) * 128 + kq * 32, qrB, qfB, oaccB, lsumB, kq, hi, l32);
    }
    asm volatile("s_waitcnt vmcnt(0)" ::: "memory");
    __builtin_amdgcn_s_barrier();
    attn_kt(smem + ((NSLOT - 1) % 3) * 16384,
            (NSLOT - 2 - qtA) * 128 + kq * 32, qrB, qfB, oaccB, lsumB, kq, hi, l32);

    // ---- per-wave l: other 16-key half of this wave's 32-key blocks in lane^32 ----
    lsumA += __shfl_xor(lsumA, 32, 64);
    lsumB += __shfl_xor(lsumB, 32, 64);

    // ---- combine kq partials via LDS (staging dead now) ----
    __syncthreads();
    float* dmp = (float*)smem;                    // [4qw][3kq][32][34] = 13056 f
    float* lP  = dmp + 13056;                     // [2m][4qw][4kq][32] = 1024 f
    if (!hi) {
        lP[((0 * 4 + qw) * 4 + kq) * 32 + l32] = lsumA;
        lP[((1 * 4 + qw) * 4 + kq) * 32 + l32] = lsumB;
    }
    // lP readers synchronize via round-0's __syncthreads below.

    #pragma unroll
    for (int r4 = 0; r4 < 4; ++r4) {
        const int m = r4 >> 1, tile = r4 & 1;
        __syncthreads();
        if (kq > 0) {
            #pragma unroll
            for (int r = 0; r < 16; r++) {
                const int dim = (r & 3) + 8 * (r >> 2) + 4 * hi;   // 0..31
                const float v = m ? oaccB[tile][r] : oaccA[tile][r];
                dmp[((qw * 3 + (kq - 1)) * 32 + l32) * 34 + dim] = v;
            }
        }
        __syncthreads();
        if (kq == 0) {
            #pragma unroll
            for (int r = 0; r < 16; r++) {
                const int dim = (r & 3) + 8 * (r >> 2) + 4 * hi;
                const float v = dmp[((qw * 3 + 0) * 32 + l32) * 34 + dim]
                              + dmp[((qw * 3 + 1) * 32 + l32) * 34 + dim]
                              + dmp[((qw * 3 + 2) * 32 + l32) * 34 + dim];
                if (m) oaccB[tile][r] += v; else oaccA[tile][r] += v;
            }
        }
    }

    if (kq == 0) {
        // slab: bf16 idx 28672 (= byte 57344, past dmp+lP), 32x72 per qw
        bf16* T8 = smem + 28672 + qw * 2304;
        #pragma unroll
        for (int m = 0; m < 2; m++) {
            float lt = 0.f;
            #pragma unroll
            for (int j = 0; j < 4; j++) lt += lP[((m * 4 + qw) * 4 + j) * 32 + l32];
            const float invl = 1.0f / lt;
            const int qrow = m ? qrB : qrA;
            #pragma unroll
            for (int tile = 0; tile < 2; tile++)
                #pragma unroll
                for (int rq = 0; rq < 4; rq++) {
                    shorts4 v4;
                    #pragma unroll
                    for (int sg = 0; sg < 4; sg++) {
                        const int r = rq * 4 + sg;
                        const float cv = m ? oaccB[tile][r] : oaccA[tile][r];
                        v4[sg] = bfbits(cv * invl);
                    }
                    *(shorts4*)(T8 + l32 * 72 + tile * 32 + rq * 8 + hi * 4) = v4;
                }
            asm volatile("s_waitcnt lgkmcnt(0)" ::: "memory");  // cross-lane RAW in-wave
            #pragma unroll
            for (int p2 = 0; p2 < 4; p2++) {
                const int rq = (lane >> 3) + p2 * 8;
                const int dd = (lane & 7) * 8;
                short8 v8 = *(const short8*)(T8 + rq * 72 + dd);
                *(short8*)(Q + (rowb + qrow + rq) * DM + hc + dd) = v8;
            }
            asm volatile("s_waitcnt lgkmcnt(0)" ::: "memory");  // drain before slab reuse
        }
    }
}

extern "C" void kernel_launch(void* const* d_in, const int* in_sizes, int n_in,
                              void* d_out, int out_size, void* d_ws, size_t ws_size,
                              hipStream_t stream)
{
    const float* x  = (const float*)d_in[0];
    const float* wq = (const float*)d_in[1];
    const float* wk = (const float*)d_in[2];
    const float* wv = (const float*)d_in[3];
    const float* wo = (const float*)d_in[4];
    float* out = (float*)d_out;

    // ws: q | k | vT bf16 (24 MB) [+ wob 2 MB if ws >= 26 MB]
    bf16* qb = (bf16*)d_ws;
    bf16* kb = qb + (size_t)OUTN;
    bf16* vb = kb + (size_t)OUTN;

    // d_out doubles as bf16 scratch until the final GEMM overwrites it
    bf16* xb  = (bf16*)d_out;
    bf16* wqb = xb + (size_t)OUTN;
    bf16* wkb = wqb + WN;
    bf16* wvb = wkb + WN;

    const bool wsBig = ws_size >= (size_t)(3 * (size_t)OUTN + WN) * sizeof(bf16); // 26 MB

    if (wsBig) {
        bf16* wob = vb + (size_t)OUTN;     // ws+24MB, untouched by qkv/attn
        cvt_all<<<(OUTN + 4 * WN) / (8 * 256), 256, 0, stream>>>(
            x, wq, wk, wv, wo, xb, wob);
        gemm_mfma<0, 3><<<dim3(DM / 128, MROWS / 128), dim3(512), 0, stream>>>(
            xb, wqb, wkb, wvb, qb, kb, vb, nullptr);
        attn_flash<<<dim3(8, NH, BATCH), dim3(1024), 0, stream>>>(qb, kb, vb);
        gemm_mfma<1, 1><<<dim3(DM / 128, MROWS / 128), dim3(512), 0, stream>>>(
            qb, wob, nullptr, nullptr, nullptr, nullptr, nullptr, out);
    } else {
        cvt_inputs<<<(OUTN + 3 * WN) / (8 * 256), 256, 0, stream>>>(x, wq, wk, wv, xb);
        gemm_mfma<0, 3><<<dim3(DM / 128, MROWS / 128), dim3(512), 0, stream>>>(
            xb, wqb, wkb, wvb, qb, kb, vb, nullptr);
        attn_flash<<<dim3(8, NH, BATCH), dim3(1024), 0, stream>>>(qb, kb, vb);
        bf16* wob = kb;    // kb dead after attention
        cvt_wo<<<WN / (8 * 256), 256, 0, stream>>>(wo, wob);
        gemm_mfma<1, 1><<<dim3(DM / 128, MROWS / 128), dim3(512), 0, stream>>>(
            qb, wob, nullptr, nullptr, nullptr, nullptr, nullptr, out);
    }
}

// Round 12
// 167.617 us; speedup vs baseline: 1.2540x; 1.2540x over previous
//
#include <hip/hip_runtime.h>
#include <hip/hip_bf16.h>
#include <stdint.h>

using bf16 = __hip_bfloat16;
typedef __attribute__((ext_vector_type(4))) short shorts4;
typedef __attribute__((ext_vector_type(8))) short short8;
typedef __attribute__((ext_vector_type(4))) float floatx4;
typedef __attribute__((ext_vector_type(16))) float floatx16;
typedef __attribute__((ext_vector_type(4))) unsigned int uintx4;

constexpr int BATCH = 2;
constexpr int SEQ   = 2048;
constexpr int NH    = 16;
constexpr int DH    = 64;
constexpr int DM    = 1024;
constexpr int MROWS = BATCH * SEQ;        // 4096
constexpr int OUTN  = MROWS * DM;         // 4194304
constexpr int WN    = DM * DM;            // 1048576

__device__ inline short bfbits(float x) {
    bf16 h = __float2bfloat16(x);
    return __builtin_bit_cast(short, h);
}

__device__ inline unsigned pack2(float a, float b) {
    return (unsigned)(unsigned short)bfbits(a) |
           ((unsigned)(unsigned short)bfbits(b) << 16);
}

// async global->LDS, 16B per lane (m97 pattern; dest = wave base + lane*16)
__device__ inline void async16(bf16* lds, const bf16* g) {
    __builtin_amdgcn_global_load_lds(
        (const __attribute__((address_space(1))) unsigned int*)g,
        (__attribute__((address_space(3))) unsigned int*)lds, 16, 0, 0);
}

__device__ inline void cvt8(const float* src, bf16* dst) {
    float4 f0 = *(const float4*)(src);
    float4 f1 = *(const float4*)(src + 4);
    short8 o;
    o[0] = bfbits(f0.x); o[1] = bfbits(f0.y); o[2] = bfbits(f0.z); o[3] = bfbits(f0.w);
    o[4] = bfbits(f1.x); o[5] = bfbits(f1.y); o[6] = bfbits(f1.z); o[7] = bfbits(f1.w);
    *(short8*)(dst) = o;
}

// ============ fp32 -> bf16 pre-convert (merged: all 5 tensors, 1 dispatch) ============
__global__ __launch_bounds__(256)
void cvt_all(const float* __restrict__ x,  const float* __restrict__ wq,
             const float* __restrict__ wk, const float* __restrict__ wv,
             const float* __restrict__ wo, bf16* __restrict__ dst,
             bf16* __restrict__ wob)
{
    const size_t i = ((size_t)blockIdx.x * 256 + threadIdx.x) * 8;
    if (i < (size_t)OUTN + 3 * WN) {
        const float* src; size_t off;
        if (i < (size_t)OUTN)               { src = x;  off = i; }
        else if (i < (size_t)OUTN + WN)     { src = wq; off = i - OUTN; }
        else if (i < (size_t)OUTN + 2 * WN) { src = wk; off = i - OUTN - WN; }
        else                                { src = wv; off = i - OUTN - 2 * (size_t)WN; }
        cvt8(src + off, dst + i);
    } else {
        const size_t off = i - OUTN - 3 * (size_t)WN;
        cvt8(wo + off, wob + off);
    }
}

// fallback path kernels (ws < 26 MB)
__global__ __launch_bounds__(256)
void cvt_inputs(const float* __restrict__ x,  const float* __restrict__ wq,
                const float* __restrict__ wk, const float* __restrict__ wv,
                bf16* __restrict__ dst)
{
    const size_t i = ((size_t)blockIdx.x * 256 + threadIdx.x) * 8;
    const float* src; size_t off;
    if (i < (size_t)OUTN)               { src = x;  off = i; }
    else if (i < (size_t)OUTN + WN)     { src = wq; off = i - OUTN; }
    else if (i < (size_t)OUTN + 2 * WN) { src = wk; off = i - OUTN - WN; }
    else                                { src = wv; off = i - OUTN - 2 * (size_t)WN; }
    cvt8(src + off, dst + i);
}

__global__ __launch_bounds__(256)
void cvt_wo(const float* __restrict__ wo, bf16* __restrict__ dst)
{
    const size_t i = ((size_t)blockIdx.x * 256 + threadIdx.x) * 8;
    cvt8(wo + i, dst + i);
}

// ============ bf16 MFMA GEMM, fused-z, 512 thr, BK=64 dbuf 2ph (R4-verified) ============
// MODE 0 (NZ=3): A=xb; z0 -> q PRESCALED, z1 -> k, z2 -> V^T packed stores.
// MODE 1 (NZ=1): A=attn-out; output fp32 row-major.
template<int MODE, int NZ>
__global__ __launch_bounds__(512, 2)
void gemm_mfma(const bf16* __restrict__ A,
               const bf16* __restrict__ W0, const bf16* __restrict__ W1,
               const bf16* __restrict__ W2,
               bf16* __restrict__ C0, bf16* __restrict__ C1, bf16* __restrict__ C2,
               float* __restrict__ F)
{
    __shared__ __align__(16) bf16 smem[(1 + NZ) * 8192 * 2];

    const int t    = threadIdx.x;
    const int wave = t >> 6;
    const int lane = t & 63;
    const int quad = lane >> 4;
    const int l16  = lane & 15;
    const int m0 = blockIdx.y * 128;
    const int n0 = blockIdx.x * 128;
    const int wr = (wave >> 2) * 64;     // 2 row-groups
    const int wc = (wave & 3) * 32;      // 4 col-groups

    const bf16* Wp[3] = {W0, W1, W2};

    floatx4 acc[NZ][4][2] = {};

    auto stage = [&](int kt, int bb) {
        bf16* Bb = smem + bb * (1 + NZ) * 8192;
        const int k0 = kt * 64;
        #pragma unroll
        for (int p = 0; p < 2; p++) {
            const int ck = p * 512 + t;            // 1024 chunks per tensor
            const int kr = ck >> 3;
            const int kg = (ck & 7) ^ (kr & 7);
            async16(Bb + ck * 8, A + (size_t)(m0 + kr) * DM + k0 + kg * 8);
            #pragma unroll
            for (int zz = 0; zz < NZ; zz++)
                async16(Bb + (1 + zz) * 8192 + ck * 8,
                        Wp[zz] + (size_t)(n0 + kr) * DM + k0 + kg * 8);
        }
    };

    stage(0, 0);
    __syncthreads();                       // prologue drain: tile 0 resident

    for (int kt = 0; kt < DM / 64; ++kt) {
        const int cur = kt & 1;
        if (kt + 1 < DM / 64) stage(kt + 1, cur ^ 1);   // prefetch BEFORE compute

        const bf16* Bb = smem + cur * (1 + NZ) * 8192;

        #pragma unroll
        for (int ks = 0; ks < 2; ks++) {
            short8 af[4];
            #pragma unroll
            for (int i = 0; i < 4; i++) {
                const int r = wr + i * 16 + l16;
                af[i] = *(const short8*)(Bb + r * 64 + ((ks * 4 + quad) ^ (r & 7)) * 8);
            }
            #pragma unroll
            for (int zz = 0; zz < NZ; zz++) {
                short8 wf[2];
                #pragma unroll
                for (int j = 0; j < 2; j++) {
                    const int n = wc + j * 16 + l16;
                    wf[j] = *(const short8*)(Bb + (1 + zz) * 8192 + n * 64 +
                                             ((ks * 4 + quad) ^ (n & 7)) * 8);
                }
                __builtin_amdgcn_s_setprio(1);
                #pragma unroll
                for (int i = 0; i < 4; i++)
                    #pragma unroll
                    for (int j = 0; j < 2; j++)
                        acc[zz][i][j] = __builtin_amdgcn_mfma_f32_16x16x32_bf16(
                            af[i], wf[j], acc[zz][i][j], 0, 0, 0);
                __builtin_amdgcn_s_setprio(0);
            }
        }
        __syncthreads();   // all waves done with cur; prefetched tile resident
    }

    // ---- epilogue (C/D layout: col=lane&15, row=quad*4+reg [m89/m91]) ----
    #pragma unroll
    for (int zz = 0; zz < NZ; zz++) {
        #pragma unroll
        for (int i = 0; i < 4; i++) {
            #pragma unroll
            for (int j = 0; j < 2; j++) {
                if (MODE == 0 && zz == 2) {
                    // V^T [B,H,DH,S]: r <-> consecutive s -> packed 8B store
                    const int s0 = m0 + wr + i * 16 + quad * 4;
                    const int gn = n0 + wc + j * 16 + l16;
                    const int b = s0 >> 11, sr = s0 & (SEQ - 1);
                    const int h = gn >> 6,  d = gn & (DH - 1);
                    shorts4 pv;
                    #pragma unroll
                    for (int r = 0; r < 4; r++) pv[r] = bfbits(acc[zz][i][j][r]);
                    *(shorts4*)(C2 + (((size_t)(b * NH + h)) * DH + d) * SEQ + sr) = pv;
                } else {
                    #pragma unroll
                    for (int r = 0; r < 4; r++) {
                        const int gm = m0 + wr + i * 16 + quad * 4 + r;
                        const int gn = n0 + wc + j * 16 + l16;
                        if (MODE == 1) {
                            F[(size_t)gm * DM + gn] = acc[zz][i][j][r];    // fp32
                        } else {
                            float av = acc[zz][i][j][r];
                            if (zz == 0) av *= 0.18033688f;  // (1/sqrt(DH))*log2(e)
                            bf16* dst = (zz == 0) ? C0 : C1;
                            dst[(size_t)gm * DM + gn] = __float2bfloat16(av);
                        }
                    }
                }
            }
        }
    }
}

// ============ attn compute tile: FORCEINLINE, accumulators by array-reference ============
__device__ __forceinline__ void attn_tile(const bf16* Ks, int kbase, int qrow,
                                          const short8 (&qf)[4],
                                          floatx16 (&oacc)[2], float& lsum,
                                          int khalf, int hi, int l32)
{
    if (kbase > qrow + 31) return;
    const bf16* Vs = Ks + 8192;
    const int qg = qrow + l32;

    #pragma unroll
    for (int kt = 0; kt < 2; kt++) {
        const int kb = kbase + kt * 32;
        if (kb > qrow + 31) continue;

        // ---- QK^T: S^T[32 keys][32 q] ----
        const int krow = khalf * 64 + kt * 32 + l32;
        floatx16 sc = {};
        #pragma unroll
        for (int sg = 0; sg < 4; sg++) {
            const int g = (sg * 2 + hi) ^ (krow & 7);
            short8 kf = *(const short8*)(Ks + krow * 64 + g * 8);
            sc = __builtin_amdgcn_mfma_f32_32x32x16_bf16(kf, qf[sg], sc, 0, 0, 0);
        }

        // ---- causal mask on diagonal tiles ----
        if (kb + 31 > qrow) {
            #pragma unroll
            for (int r = 0; r < 16; r++) {
                const int key = kb + (r & 3) + 8 * (r >> 2) + 4 * hi;
                sc[r] = (key <= qg) ? sc[r] : -1e30f;
            }
        }

        // ---- p = exp2(s), partial l ----
        #pragma unroll
        for (int r = 0; r < 16; r++) {
            const float p = __builtin_amdgcn_exp2f(sc[r]);
            sc[r] = p;
            lsum += p;
        }

        // ---- pack P pairs: d[g][i] = keys 8g+4hi+2i+{0,1} (q = l32) ----
        unsigned d[4][2];
        #pragma unroll
        for (int g = 0; g < 4; g++) {
            d[g][0] = pack2(sc[4 * g + 0], sc[4 * g + 1]);
            d[g][1] = pack2(sc[4 * g + 2], sc[4 * g + 3]);
        }

        // ---- PV per 16-key segment: one shfl_xor(32) pair builds B-frag ----
        #pragma unroll
        for (int h16 = 0; h16 < 2; h16++) {
            const unsigned a0 = d[h16 * 2][0],     a1 = d[h16 * 2][1];
            const unsigned b0 = d[h16 * 2 + 1][0], b1 = d[h16 * 2 + 1][1];
            const unsigned mine0 = hi ? b0 : a0, mine1 = hi ? b1 : a1;
            const unsigned give0 = hi ? a0 : b0, give1 = hi ? a1 : b1;
            const unsigned r0 = (unsigned)__shfl_xor((int)give0, 32, 64);
            const unsigned r1 = (unsigned)__shfl_xor((int)give1, 32, 64);
            uintx4 pw;
            pw[0] = hi ? r0 : mine0;
            pw[1] = hi ? r1 : mine1;
            pw[2] = hi ? mine0 : r0;
            pw[3] = hi ? mine1 : r1;
            short8 pb = __builtin_bit_cast(short8, pw);

            const int Gbase = khalf * 8 + kt * 4 + h16 * 2 + hi;
            #pragma unroll
            for (int tile = 0; tile < 2; tile++) {
                const int vrow = tile * 32 + l32;
                const int vg = Gbase ^ (vrow & 15);
                short8 vf = *(const short8*)(Vs + vrow * 128 + vg * 8);
                oacc[tile] = __builtin_amdgcn_mfma_f32_32x32x16_bf16(vf, pb, oacc[tile], 0, 0, 0);
            }
        }
    }
}

// ============ MFMA causal flash attention: 2-blocks/CU oversubscription + XCD pin ============
// R10/R11's 1024-thr variant killed containers twice each (unexplained; abandoned).
// This round: R4's VERIFIED 512-thr/8-wave/64KB-dbuf loop (1 barrier per slot,
// prefetch-before-compute) + R8's XCD-pin, with the TLP restored the way R2
// proved works: 512 blocks at 2 blocks/CU (dynamic scheduling also smooths the
// causal imbalance; LPT ordering dispatches big q-tiles first).
// Roles: qw = wave&3 (32-row q-subtile), khalf = wave>>2 (64-key half).
// Remap: xcd = id&7 -> all 16 q-tiles of one (h,b) share an XCD (K/V 512KB x4
// = 2MB < 4MB L2). qt = 15-(jj&15): work ~ qt+1 descending in dispatch order.
// Q,K row-major [B,S,DM] (q prescaled by 0.125*log2e); V^T [B,H,DH,S].
// 32x32 layouts (m74/m101): C/D col=lane&31, row=(r&3)+8*(r>>2)+4*(lane>>5).
__global__ __launch_bounds__(512, 4)
void attn_flash(bf16* __restrict__ Q, const bf16* __restrict__ K,
                const bf16* __restrict__ Vt)
{
    // 64KB: 2 x (Ks[128][64] g^=row&7 | Vs[64][128] g^=row&15) -> 2 blocks/CU.
    // Epilogue reuse: fp32 dump [4][32][65] + l[128] + bf16 slabs @16896.
    __shared__ __align__(16) bf16 smem[32768];

    const int t    = threadIdx.x;
    const int wave = t >> 6;
    const int lane = t & 63;
    const int hi   = lane >> 5;
    const int l32  = lane & 31;

    // ---- XCD-pin + LPT remap (bijective on 512 blocks) ----
    const int id  = blockIdx.x + 16 * (blockIdx.y + NH * blockIdx.z);
    const int xcd = id & 7;
    const int jj  = id >> 3;               // 0..63
    const int hb  = xcd * 4 + (jj >> 4);   // 0..31
    const int h   = hb & (NH - 1);
    const int b   = hb >> 4;
    const int qt  = 15 - (jj & 15);        // LPT: big tiles dispatch first
    const int q0  = qt * 128;

    const int hc  = h * DH;
    const size_t rowb = (size_t)b * SEQ;
    const size_t bhv  = ((size_t)(b * NH + h)) * SEQ * DH;

    const int qw    = wave & 3;            // q-subtile
    const int khalf = wave >> 2;           // 64-key half
    const int qrow  = q0 + qw * 32;

    short8 qf[4];
    #pragma unroll
    for (int sg = 0; sg < 4; sg++)
        qf[sg] = *(const short8*)(Q + (rowb + qrow + l32) * DM + hc + sg * 16 + hi * 8);

    floatx16 oacc[2] = {};
    float lsum = 0.f;

    const int T = qt + 1;                  // 128-key slots

    auto stage = [&](int tt, int bb) {
        bf16* Kb = smem + bb * 16384;
        bf16* Vb = Kb + 8192;
        const int k0 = tt * 128;
        #pragma unroll
        for (int p = 0; p < 2; p++) {
            const int ck = p * 512 + t;
            const int kr = ck >> 3;
            const int kg = (ck & 7) ^ (kr & 7);
            async16(Kb + ck * 8, K + (rowb + k0 + kr) * DM + hc + kg * 8);
            const int vr = ck >> 4;
            const int vg = (ck & 15) ^ (vr & 15);
            async16(Vb + ck * 8, Vt + bhv + (size_t)vr * SEQ + k0 + vg * 8);
        }
    };

    stage(0, 0);
    __syncthreads();                       // prologue drain: slot 0 resident

    for (int tt = 0; tt < T; ++tt) {
        const int cur = tt & 1;
        if (tt + 1 < T) stage(tt + 1, cur ^ 1);   // prefetch BEFORE compute
        attn_tile(smem + cur * 16384, tt * 128 + khalf * 64, qrow, qf,
                  oacc, lsum, khalf, hi, l32);
        __syncthreads();   // all waves done with cur; prefetched slot resident
    }

    // ---- per-wave l: other 16-key half of this wave's range is in lane^32 ----
    lsum += __shfl_xor(lsum, 32, 64);

    // ---- combine khalf pair via LDS (staging dead now) ----
    __syncthreads();
    float* dmp = (float*)smem;                 // [4][32][65] = 8320 f
    float* lP  = dmp + 4 * 32 * 65;            // 128 f
    if (wave >= 4) {
        const int p = wave - 4;
        #pragma unroll
        for (int tile = 0; tile < 2; tile++)
            #pragma unroll
            for (int r = 0; r < 16; r++) {
                const int d = tile * 32 + (r & 3) + 8 * (r >> 2) + 4 * hi;
                dmp[(p * 32 + l32) * 65 + d] = oacc[tile][r];
            }
        if (!hi) lP[p * 32 + l32] = lsum;
    }
    __syncthreads();

    if (wave < 4) {
        const int p = wave;
        lsum += lP[p * 32 + l32];
        const float invl = 1.0f / lsum;

        // slabs after dump region: bf16 offset 16896 (= float 8448)
        bf16* T8 = smem + 16896 + wave * (32 * 72);
        #pragma unroll
        for (int tile = 0; tile < 2; tile++)
            #pragma unroll
            for (int rq = 0; rq < 4; rq++) {
                shorts4 v4;
                #pragma unroll
                for (int sg = 0; sg < 4; sg++) {
                    const int r = rq * 4 + sg;
                    const int d = tile * 32 + (r & 3) + 8 * (r >> 2) + 4 * hi;
                    const float comb = oacc[tile][r] + dmp[(p * 32 + l32) * 65 + d];
                    v4[sg] = bfbits(comb * invl);
                }
                *(shorts4*)(T8 + l32 * 72 + tile * 32 + rq * 8 + hi * 4) = v4;
            }
        asm volatile("s_waitcnt lgkmcnt(0)" ::: "memory");  // cross-lane RAW in-wave
        #pragma unroll
        for (int p2 = 0; p2 < 4; p2++) {
            const int rq = (lane >> 3) + p2 * 8;
            const int dd = (lane & 7) * 8;
            short8 v8 = *(const short8*)(T8 + rq * 72 + dd);
            *(short8*)(Q + (rowb + qrow + rq) * DM + hc + dd) = v8;
        }
    }
}

extern "C" void kernel_launch(void* const* d_in, const int* in_sizes, int n_in,
                              void* d_out, int out_size, void* d_ws, size_t ws_size,
                              hipStream_t stream)
{
    const float* x  = (const float*)d_in[0];
    const float* wq = (const float*)d_in[1];
    const float* wk = (const float*)d_in[2];
    const float* wv = (const float*)d_in[3];
    const float* wo = (const float*)d_in[4];
    float* out = (float*)d_out;

    // ws: q | k | vT bf16 (24 MB) [+ wob 2 MB if ws >= 26 MB]
    bf16* qb = (bf16*)d_ws;
    bf16* kb = qb + (size_t)OUTN;
    bf16* vb = kb + (size_t)OUTN;

    // d_out doubles as bf16 scratch until the final GEMM overwrites it
    bf16* xb  = (bf16*)d_out;
    bf16* wqb = xb + (size_t)OUTN;
    bf16* wkb = wqb + WN;
    bf16* wvb = wkb + WN;

    const bool wsBig = ws_size >= (size_t)(3 * (size_t)OUTN + WN) * sizeof(bf16); // 26 MB

    if (wsBig) {
        bf16* wob = vb + (size_t)OUTN;     // ws+24MB, untouched by qkv/attn
        cvt_all<<<(OUTN + 4 * WN) / (8 * 256), 256, 0, stream>>>(
            x, wq, wk, wv, wo, xb, wob);
        gemm_mfma<0, 3><<<dim3(DM / 128, MROWS / 128), dim3(512), 0, stream>>>(
            xb, wqb, wkb, wvb, qb, kb, vb, nullptr);
        attn_flash<<<dim3(16, NH, BATCH), dim3(512), 0, stream>>>(qb, kb, vb);
        gemm_mfma<1, 1><<<dim3(DM / 128, MROWS / 128), dim3(512), 0, stream>>>(
            qb, wob, nullptr, nullptr, nullptr, nullptr, nullptr, out);
    } else {
        cvt_inputs<<<(OUTN + 3 * WN) / (8 * 256), 256, 0, stream>>>(x, wq, wk, wv, xb);
        gemm_mfma<0, 3><<<dim3(DM / 128, MROWS / 128), dim3(512), 0, stream>>>(
            xb, wqb, wkb, wvb, qb, kb, vb, nullptr);
        attn_flash<<<dim3(16, NH, BATCH), dim3(512), 0, stream>>>(qb, kb, vb);
        bf16* wob = kb;    // kb dead after attention
        cvt_wo<<<WN / (8 * 256), 256, 0, stream>>>(wo, wob);
        gemm_mfma<1, 1><<<dim3(DM / 128, MROWS / 128), dim3(512), 0, stream>>>(
            qb, wob, nullptr, nullptr, nullptr, nullptr, nullptr, out);
    }
}

// Round 14
// 161.144 us; speedup vs baseline: 1.3044x; 1.0402x over previous
//
#include <hip/hip_runtime.h>
#include <hip/hip_bf16.h>
#include <stdint.h>

using bf16 = __hip_bfloat16;
typedef __attribute__((ext_vector_type(4))) short shorts4;
typedef __attribute__((ext_vector_type(8))) short short8;
typedef __attribute__((ext_vector_type(4))) float floatx4;
typedef __attribute__((ext_vector_type(16))) float floatx16;
typedef __attribute__((ext_vector_type(4))) unsigned int uintx4;

constexpr int BATCH = 2;
constexpr int SEQ   = 2048;
constexpr int NH    = 16;
constexpr int DH    = 64;
constexpr int DM    = 1024;
constexpr int MROWS = BATCH * SEQ;        // 4096
constexpr int OUTN  = MROWS * DM;         // 4194304
constexpr int WN    = DM * DM;            // 1048576

__device__ inline short bfbits(float x) {
    bf16 h = __float2bfloat16(x);
    return __builtin_bit_cast(short, h);
}

__device__ inline unsigned pack2(float a, float b) {
    return (unsigned)(unsigned short)bfbits(a) |
           ((unsigned)(unsigned short)bfbits(b) << 16);
}

// async global->LDS, 16B per lane (m97 pattern; dest = wave base + lane*16)
__device__ inline void async16(bf16* lds, const bf16* g) {
    __builtin_amdgcn_global_load_lds(
        (const __attribute__((address_space(1))) unsigned int*)g,
        (__attribute__((address_space(3))) unsigned int*)lds, 16, 0, 0);
}

__device__ inline void cvt8(const float* src, bf16* dst) {
    float4 f0 = *(const float4*)(src);
    float4 f1 = *(const float4*)(src + 4);
    short8 o;
    o[0] = bfbits(f0.x); o[1] = bfbits(f0.y); o[2] = bfbits(f0.z); o[3] = bfbits(f0.w);
    o[4] = bfbits(f1.x); o[5] = bfbits(f1.y); o[6] = bfbits(f1.z); o[7] = bfbits(f1.w);
    *(short8*)(dst) = o;
}

// ============ fp32 -> bf16 pre-convert (merged: all 5 tensors, 1 dispatch) ============
__global__ __launch_bounds__(256)
void cvt_all(const float* __restrict__ x,  const float* __restrict__ wq,
             const float* __restrict__ wk, const float* __restrict__ wv,
             const float* __restrict__ wo, bf16* __restrict__ dst,
             bf16* __restrict__ wob)
{
    const size_t i = ((size_t)blockIdx.x * 256 + threadIdx.x) * 8;
    if (i < (size_t)OUTN + 3 * WN) {
        const float* src; size_t off;
        if (i < (size_t)OUTN)               { src = x;  off = i; }
        else if (i < (size_t)OUTN + WN)     { src = wq; off = i - OUTN; }
        else if (i < (size_t)OUTN + 2 * WN) { src = wk; off = i - OUTN - WN; }
        else                                { src = wv; off = i - OUTN - 2 * (size_t)WN; }
        cvt8(src + off, dst + i);
    } else {
        const size_t off = i - OUTN - 3 * (size_t)WN;
        cvt8(wo + off, wob + off);
    }
}

// fallback path kernels (ws < 26 MB)
__global__ __launch_bounds__(256)
void cvt_inputs(const float* __restrict__ x,  const float* __restrict__ wq,
                const float* __restrict__ wk, const float* __restrict__ wv,
                bf16* __restrict__ dst)
{
    const size_t i = ((size_t)blockIdx.x * 256 + threadIdx.x) * 8;
    const float* src; size_t off;
    if (i < (size_t)OUTN)               { src = x;  off = i; }
    else if (i < (size_t)OUTN + WN)     { src = wq; off = i - OUTN; }
    else if (i < (size_t)OUTN + 2 * WN) { src = wk; off = i - OUTN - WN; }
    else                                { src = wv; off = i - OUTN - 2 * (size_t)WN; }
    cvt8(src + off, dst + i);
}

__global__ __launch_bounds__(256)
void cvt_wo(const float* __restrict__ wo, bf16* __restrict__ dst)
{
    const size_t i = ((size_t)blockIdx.x * 256 + threadIdx.x) * 8;
    cvt8(wo + i, dst + i);
}

// ============ bf16 MFMA GEMM, fused-z, tri-buffer counted-vmcnt (R14, LDS-correct) ============
// R13's schedule (the mechanism R12 proved: counted vmcnt + tri-buffer, no
// per-tile vmcnt(0) drain) with geometry that FITS LDS: NZ=3 uses BK=32
// (4 tensors x 8KB x 3 bufs = 96KB), NZ=1 uses BK=64 (2 x 16KB x 3 = 96KB).
// Per K-tile: {wait own vmcnt(VM) -> s_barrier (all waves' tile resident)
// -> stage(kt+2) -> compute}. stage(kt+2) overwrites buf (kt-1)%3, consumed
// in compute(kt-1) before this barrier -> safe (R8-attn proof). Last tile
// drains vmcnt(0). Swizzle involution mask = groups/row - 1 on BOTH sides.
// MODE 0 (NZ=3): A=xb; z0 -> q PRESCALED, z1 -> k, z2 -> V^T packed stores.
// MODE 1 (NZ=1): A=attn-out; output fp32 row-major.
template<int MODE, int NZ>
__global__ __launch_bounds__(512, 2)
void gemm_mfma(const bf16* __restrict__ A,
               const bf16* __restrict__ W0, const bf16* __restrict__ W1,
               const bf16* __restrict__ W2,
               bf16* __restrict__ C0, bf16* __restrict__ C1, bf16* __restrict__ C2,
               float* __restrict__ F)
{
    constexpr int BK   = (NZ == 3) ? 32 : 64;  // K-step
    constexpr int GR   = BK / 8;               // 16B groups per row
    constexpr int SWM  = GR - 1;               // swizzle mask
    constexpr int TEN  = 1 + NZ;               // tensors per stage
    constexpr int TB   = 128 * BK;             // bf16 per tensor tile
    constexpr int RNDS = BK / 32;              // 512-thread rounds per tensor
    constexpr int VM   = RNDS * TEN;           // async16 per thread per stage
    constexpr int NT   = DM / BK;              // K-tiles
    constexpr int LG   = (GR == 4) ? 2 : 3;    // log2(GR)

    __shared__ __align__(16) bf16 smem[TEN * TB * 3];   // 96KB both configs

    const int t    = threadIdx.x;
    const int wave = t >> 6;
    const int lane = t & 63;
    const int quad = lane >> 4;
    const int l16  = lane & 15;
    const int m0 = blockIdx.y * 128;
    const int n0 = blockIdx.x * 128;
    const int wr = (wave >> 2) * 64;     // 2 row-groups
    const int wc = (wave & 3) * 32;      // 4 col-groups

    const bf16* Wp[3] = {W0, W1, W2};

    floatx4 acc[NZ][4][2] = {};

    auto stage = [&](int kt) {
        bf16* Bb = smem + (kt % 3) * TEN * TB;
        const int k0 = kt * BK;
        #pragma unroll
        for (int p = 0; p < RNDS; p++) {
            const int ck = p * 512 + t;            // chunk id within tensor
            const int kr = ck >> LG;               // row 0..127
            const int kg = (ck & SWM) ^ (kr & SWM);
            async16(Bb + ck * 8, A + (size_t)(m0 + kr) * DM + k0 + kg * 8);
            #pragma unroll
            for (int zz = 0; zz < NZ; zz++)
                async16(Bb + (1 + zz) * TB + ck * 8,
                        Wp[zz] + (size_t)(n0 + kr) * DM + k0 + kg * 8);
        }
    };

    stage(0);
    stage(1);

    for (int kt = 0; kt < NT; ++kt) {
        if (kt < NT - 1) asm volatile("s_waitcnt vmcnt(%0)" :: "i"(VM) : "memory");
        else             asm volatile("s_waitcnt vmcnt(0)" ::: "memory");
        __builtin_amdgcn_s_barrier();          // all waves' tile kt resident
        if (kt + 2 < NT) stage(kt + 2);        // overwrites buf (kt-1)%3: safe

        const bf16* Bb = smem + (kt % 3) * TEN * TB;

        #pragma unroll
        for (int ks = 0; ks < BK / 32; ks++) {
            short8 af[4];
            #pragma unroll
            for (int i = 0; i < 4; i++) {
                const int r = wr + i * 16 + l16;
                const int g = (ks * 4 + quad) ^ (r & SWM);
                af[i] = *(const short8*)(Bb + r * BK + g * 8);
            }
            #pragma unroll
            for (int zz = 0; zz < NZ; zz++) {
                short8 wf[2];
                #pragma unroll
                for (int j = 0; j < 2; j++) {
                    const int n = wc + j * 16 + l16;
                    const int g = (ks * 4 + quad) ^ (n & SWM);
                    wf[j] = *(const short8*)(Bb + (1 + zz) * TB + n * BK + g * 8);
                }
                __builtin_amdgcn_s_setprio(1);
                #pragma unroll
                for (int i = 0; i < 4; i++)
                    #pragma unroll
                    for (int j = 0; j < 2; j++)
                        acc[zz][i][j] = __builtin_amdgcn_mfma_f32_16x16x32_bf16(
                            af[i], wf[j], acc[zz][i][j], 0, 0, 0);
                __builtin_amdgcn_s_setprio(0);
            }
        }
        // no trailing barrier: next iteration's barrier is the join
    }

    // ---- epilogue (C/D layout: col=lane&15, row=quad*4+reg [m89/m91]) ----
    #pragma unroll
    for (int zz = 0; zz < NZ; zz++) {
        #pragma unroll
        for (int i = 0; i < 4; i++) {
            #pragma unroll
            for (int j = 0; j < 2; j++) {
                if (MODE == 0 && zz == 2) {
                    // V^T [B,H,DH,S]: r <-> consecutive s -> packed 8B store
                    const int s0 = m0 + wr + i * 16 + quad * 4;
                    const int gn = n0 + wc + j * 16 + l16;
                    const int b = s0 >> 11, sr = s0 & (SEQ - 1);
                    const int h = gn >> 6,  d = gn & (DH - 1);
                    shorts4 pv;
                    #pragma unroll
                    for (int r = 0; r < 4; r++) pv[r] = bfbits(acc[zz][i][j][r]);
                    *(shorts4*)(C2 + (((size_t)(b * NH + h)) * DH + d) * SEQ + sr) = pv;
                } else {
                    #pragma unroll
                    for (int r = 0; r < 4; r++) {
                        const int gm = m0 + wr + i * 16 + quad * 4 + r;
                        const int gn = n0 + wc + j * 16 + l16;
                        if (MODE == 1) {
                            F[(size_t)gm * DM + gn] = acc[zz][i][j][r];    // fp32
                        } else {
                            float av = acc[zz][i][j][r];
                            if (zz == 0) av *= 0.18033688f;  // (1/sqrt(DH))*log2(e)
                            bf16* dst = (zz == 0) ? C0 : C1;
                            dst[(size_t)gm * DM + gn] = __float2bfloat16(av);
                        }
                    }
                }
            }
        }
    }
}

// ============ attn compute tile: FORCEINLINE, accumulators by array-reference ============
__device__ __forceinline__ void attn_tile(const bf16* Ks, int kbase, int qrow,
                                          const short8 (&qf)[4],
                                          floatx16 (&oacc)[2], float& lsum,
                                          int khalf, int hi, int l32)
{
    if (kbase > qrow + 31) return;
    const bf16* Vs = Ks + 8192;
    const int qg = qrow + l32;

    #pragma unroll
    for (int kt = 0; kt < 2; kt++) {
        const int kb = kbase + kt * 32;
        if (kb > qrow + 31) continue;

        // ---- QK^T: S^T[32 keys][32 q] ----
        const int krow = khalf * 64 + kt * 32 + l32;
        floatx16 sc = {};
        #pragma unroll
        for (int sg = 0; sg < 4; sg++) {
            const int g = (sg * 2 + hi) ^ (krow & 7);
            short8 kf = *(const short8*)(Ks + krow * 64 + g * 8);
            sc = __builtin_amdgcn_mfma_f32_32x32x16_bf16(kf, qf[sg], sc, 0, 0, 0);
        }

        // ---- causal mask on diagonal tiles ----
        if (kb + 31 > qrow) {
            #pragma unroll
            for (int r = 0; r < 16; r++) {
                const int key = kb + (r & 3) + 8 * (r >> 2) + 4 * hi;
                sc[r] = (key <= qg) ? sc[r] : -1e30f;
            }
        }

        // ---- p = exp2(s), partial l ----
        #pragma unroll
        for (int r = 0; r < 16; r++) {
            const float p = __builtin_amdgcn_exp2f(sc[r]);
            sc[r] = p;
            lsum += p;
        }

        // ---- pack P pairs: d[g][i] = keys 8g+4hi+2i+{0,1} (q = l32) ----
        unsigned d[4][2];
        #pragma unroll
        for (int g = 0; g < 4; g++) {
            d[g][0] = pack2(sc[4 * g + 0], sc[4 * g + 1]);
            d[g][1] = pack2(sc[4 * g + 2], sc[4 * g + 3]);
        }

        // ---- PV per 16-key segment: one shfl_xor(32) pair builds B-frag ----
        #pragma unroll
        for (int h16 = 0; h16 < 2; h16++) {
            const unsigned a0 = d[h16 * 2][0],     a1 = d[h16 * 2][1];
            const unsigned b0 = d[h16 * 2 + 1][0], b1 = d[h16 * 2 + 1][1];
            const unsigned mine0 = hi ? b0 : a0, mine1 = hi ? b1 : a1;
            const unsigned give0 = hi ? a0 : b0, give1 = hi ? a1 : b1;
            const unsigned r0 = (unsigned)__shfl_xor((int)give0, 32, 64);
            const unsigned r1 = (unsigned)__shfl_xor((int)give1, 32, 64);
            uintx4 pw;
            pw[0] = hi ? r0 : mine0;
            pw[1] = hi ? r1 : mine1;
            pw[2] = hi ? mine0 : r0;
            pw[3] = hi ? mine1 : r1;
            short8 pb = __builtin_bit_cast(short8, pw);

            const int Gbase = khalf * 8 + kt * 4 + h16 * 2 + hi;
            #pragma unroll
            for (int tile = 0; tile < 2; tile++) {
                const int vrow = tile * 32 + l32;
                const int vg = Gbase ^ (vrow & 15);
                short8 vf = *(const short8*)(Vs + vrow * 128 + vg * 8);
                oacc[tile] = __builtin_amdgcn_mfma_f32_32x32x16_bf16(vf, pb, oacc[tile], 0, 0, 0);
            }
        }
    }
}

// ============ MFMA causal flash attention: paired q-tiles + XCD-pinned heads ============
// (R8-verified exact: best measured attn at ~40us.)
__global__ __launch_bounds__(512, 2)
void attn_flash(bf16* __restrict__ Q, const bf16* __restrict__ K,
                const bf16* __restrict__ Vt)
{
    // 96KB: 3 x (Ks[128][64] g^=row&7 | Vs[64][128] g^=row&15) stage buffers.
    __shared__ __align__(16) bf16 smem[49152];

    const int t    = threadIdx.x;
    const int wave = t >> 6;
    const int lane = t & 63;
    const int hi   = lane >> 5;
    const int l32  = lane & 31;

    // ---- XCD-pinned role remap (bijective on 256 blocks) ----
    const int id  = blockIdx.x + 8 * (blockIdx.y + NH * blockIdx.z);
    const int xcd = id & 7;
    const int jj  = id >> 3;               // 0..31
    const int p   = xcd * 4 + (jj >> 3);   // head-pair index 0..31
    const int h   = p & (NH - 1);
    const int b   = p >> 4;
    const int qtA = jj & 7;                // 0..7
    const int qtB = 15 - qtA;              // 8..15

    const int hc  = h * DH;
    const size_t rowb = (size_t)b * SEQ;
    const size_t bhv  = ((size_t)(b * NH + h)) * SEQ * DH;

    const int qw    = wave & 3;
    const int khalf = wave >> 2;
    const int qrA = qtA * 128 + qw * 32;
    const int qrB = qtB * 128 + qw * 32;

    short8 qfA[4], qfB[4];
    #pragma unroll
    for (int sg = 0; sg < 4; sg++) {
        qfA[sg] = *(const short8*)(Q + (rowb + qrA + l32) * DM + hc + sg * 16 + hi * 8);
        qfB[sg] = *(const short8*)(Q + (rowb + qrB + l32) * DM + hc + sg * 16 + hi * 8);
    }

    floatx16 oaccA[2] = {}, oaccB[2] = {};
    float lsumA = 0.f, lsumB = 0.f;

    constexpr int NSLOT = 17;

    auto slotK0 = [&](int s) { return (s <= qtA ? s : s - qtA - 1) * 128; };

    auto stage = [&](int s) {
        bf16* Kb = smem + (s % 3) * 16384;
        bf16* Vb = Kb + 8192;
        const int k0 = slotK0(s);
        #pragma unroll
        for (int pp = 0; pp < 2; pp++) {
            const int ck = pp * 512 + t;
            const int kr = ck >> 3;
            const int kg = (ck & 7) ^ (kr & 7);
            async16(Kb + ck * 8, K + (rowb + k0 + kr) * DM + hc + kg * 8);
            const int vr = ck >> 4;
            const int vg = (ck & 15) ^ (vr & 15);
            async16(Vb + ck * 8, Vt + bhv + (size_t)vr * SEQ + k0 + vg * 8);
        }
    };

    // ---- pipelined main loop: issue s+2, wait slot s (vmcnt 4), compute s ----
    stage(0);
    stage(1);
    for (int s = 0; s < NSLOT - 1; ++s) {
        asm volatile("s_waitcnt vmcnt(4)" ::: "memory");   // slot s resident (own 4)
        __builtin_amdgcn_s_barrier();                      // all lanes' slot s done
        if (s + 2 < NSLOT) stage(s + 2);
        const bf16* Ks = smem + (s % 3) * 16384;
        if (s <= qtA)
            attn_tile(Ks, s * 128 + khalf * 64, qrA, qfA, oaccA, lsumA, khalf, hi, l32);
        else
            attn_tile(Ks, (s - qtA - 1) * 128 + khalf * 64, qrB, qfB, oaccB, lsumB, khalf, hi, l32);
    }
    asm volatile("s_waitcnt vmcnt(0)" ::: "memory");
    __builtin_amdgcn_s_barrier();
    attn_tile(smem + ((NSLOT - 1) % 3) * 16384,
              (NSLOT - 2 - qtA) * 128 + khalf * 64, qrB, qfB, oaccB, lsumB, khalf, hi, l32);

    // ---- per-wave l: other 16-key half of this wave's range is in lane^32 ----
    lsumA += __shfl_xor(lsumA, 32, 64);
    lsumB += __shfl_xor(lsumB, 32, 64);

    // ---- combine khalf pair via LDS (staging dead now) ----
    __syncthreads();
    float* dmp = (float*)smem;                    // [2][4][32][66] = 16896 f
    float* lP  = dmp + 2 * 4 * 32 * 66;           // [2][4][32]     = 256 f
    if (khalf == 1) {
        #pragma unroll
        for (int m = 0; m < 2; m++) {
            const floatx16* oc = m ? oaccB : oaccA;
            #pragma unroll
            for (int tile = 0; tile < 2; tile++)
                #pragma unroll
                for (int r = 0; r < 16; r++) {
                    const int dd = tile * 32 + (r & 3) + 8 * (r >> 2) + 4 * hi;
                    dmp[((m * 4 + qw) * 32 + l32) * 66 + dd] = oc[tile][r];
                }
            if (!hi) lP[(m * 4 + qw) * 32 + l32] = m ? lsumB : lsumA;
        }
    }
    __syncthreads();

    if (khalf == 0) {
        // slabs after dump region: bf16 index 34304 (= 68608 B), 32x72 per qw
        bf16* T8 = smem + 34304 + qw * 2304;
        #pragma unroll
        for (int m = 0; m < 2; m++) {
            const floatx16* oc = m ? oaccB : oaccA;
            const float lt = (m ? lsumB : lsumA) + lP[(m * 4 + qw) * 32 + l32];
            const float invl = 1.0f / lt;
            const int qrow = m ? qrB : qrA;
            #pragma unroll
            for (int tile = 0; tile < 2; tile++)
                #pragma unroll
                for (int rq = 0; rq < 4; rq++) {
                    shorts4 v4;
                    #pragma unroll
                    for (int sg = 0; sg < 4; sg++) {
                        const int r = rq * 4 + sg;
                        const int dd = tile * 32 + (r & 3) + 8 * (r >> 2) + 4 * hi;
                        const float comb = oc[tile][r] + dmp[((m * 4 + qw) * 32 + l32) * 66 + dd];
                        v4[sg] = bfbits(comb * invl);
                    }
                    *(shorts4*)(T8 + l32 * 72 + tile * 32 + rq * 8 + hi * 4) = v4;
                }
            asm volatile("s_waitcnt lgkmcnt(0)" ::: "memory");  // cross-lane RAW in-wave
            #pragma unroll
            for (int p2 = 0; p2 < 4; p2++) {
                const int rq = (lane >> 3) + p2 * 8;
                const int dd = (lane & 7) * 8;
                short8 v8 = *(const short8*)(T8 + rq * 72 + dd);
                *(short8*)(Q + (rowb + qrow + rq) * DM + hc + dd) = v8;
            }
            asm volatile("s_waitcnt lgkmcnt(0)" ::: "memory");  // drain before slab reuse
        }
    }
}

extern "C" void kernel_launch(void* const* d_in, const int* in_sizes, int n_in,
                              void* d_out, int out_size, void* d_ws, size_t ws_size,
                              hipStream_t stream)
{
    const float* x  = (const float*)d_in[0];
    const float* wq = (const float*)d_in[1];
    const float* wk = (const float*)d_in[2];
    const float* wv = (const float*)d_in[3];
    const float* wo = (const float*)d_in[4];
    float* out = (float*)d_out;

    // ws: q | k | vT bf16 (24 MB) [+ wob 2 MB if ws >= 26 MB]
    bf16* qb = (bf16*)d_ws;
    bf16* kb = qb + (size_t)OUTN;
    bf16* vb = kb + (size_t)OUTN;

    // d_out doubles as bf16 scratch until the final GEMM overwrites it
    bf16* xb  = (bf16*)d_out;
    bf16* wqb = xb + (size_t)OUTN;
    bf16* wkb = wqb + WN;
    bf16* wvb = wkb + WN;

    const bool wsBig = ws_size >= (size_t)(3 * (size_t)OUTN + WN) * sizeof(bf16); // 26 MB

    if (wsBig) {
        bf16* wob = vb + (size_t)OUTN;     // ws+24MB, untouched by qkv/attn
        cvt_all<<<(OUTN + 4 * WN) / (8 * 256), 256, 0, stream>>>(
            x, wq, wk, wv, wo, xb, wob);
        gemm_mfma<0, 3><<<dim3(DM / 128, MROWS / 128), dim3(512), 0, stream>>>(
            xb, wqb, wkb, wvb, qb, kb, vb, nullptr);
        attn_flash<<<dim3(8, NH, BATCH), dim3(512), 0, stream>>>(qb, kb, vb);
        gemm_mfma<1, 1><<<dim3(DM / 128, MROWS / 128), dim3(512), 0, stream>>>(
            qb, wob, nullptr, nullptr, nullptr, nullptr, nullptr, out);
    } else {
        cvt_inputs<<<(OUTN + 3 * WN) / (8 * 256), 256, 0, stream>>>(x, wq, wk, wv, xb);
        gemm_mfma<0, 3><<<dim3(DM / 128, MROWS / 128), dim3(512), 0, stream>>>(
            xb, wqb, wkb, wvb, qb, kb, vb, nullptr);
        attn_flash<<<dim3(8, NH, BATCH), dim3(512), 0, stream>>>(qb, kb, vb);
        bf16* wob = kb;    // kb dead after attention
        cvt_wo<<<WN / (8 * 256), 256, 0, stream>>>(wo, wob);
        gemm_mfma<1, 1><<<dim3(DM / 128, MROWS / 128), dim3(512), 0, stream>>>(
            qb, wob, nullptr, nullptr, nullptr, nullptr, nullptr, out);
    }
}

// Round 15
// 157.269 us; speedup vs baseline: 1.3365x; 1.0246x over previous
//
#include <hip/hip_runtime.h>
#include <hip/hip_bf16.h>
#include <stdint.h>

using bf16 = __hip_bfloat16;
typedef __attribute__((ext_vector_type(4))) short shorts4;
typedef __attribute__((ext_vector_type(8))) short short8;
typedef __attribute__((ext_vector_type(4))) float floatx4;
typedef __attribute__((ext_vector_type(16))) float floatx16;
typedef __attribute__((ext_vector_type(4))) unsigned int uintx4;

constexpr int BATCH = 2;
constexpr int SEQ   = 2048;
constexpr int NH    = 16;
constexpr int DH    = 64;
constexpr int DM    = 1024;
constexpr int MROWS = BATCH * SEQ;        // 4096
constexpr int OUTN  = MROWS * DM;         // 4194304
constexpr int WN    = DM * DM;            // 1048576

__device__ inline short bfbits(float x) {
    bf16 h = __float2bfloat16(x);
    return __builtin_bit_cast(short, h);
}

__device__ inline unsigned pack2(float a, float b) {
    return (unsigned)(unsigned short)bfbits(a) |
           ((unsigned)(unsigned short)bfbits(b) << 16);
}

// async global->LDS, 16B per lane (m97 pattern; dest = wave base + lane*16)
__device__ inline void async16(bf16* lds, const bf16* g) {
    __builtin_amdgcn_global_load_lds(
        (const __attribute__((address_space(1))) unsigned int*)g,
        (__attribute__((address_space(3))) unsigned int*)lds, 16, 0, 0);
}

__device__ inline void cvt8(const float* src, bf16* dst) {
    float4 f0 = *(const float4*)(src);
    float4 f1 = *(const float4*)(src + 4);
    short8 o;
    o[0] = bfbits(f0.x); o[1] = bfbits(f0.y); o[2] = bfbits(f0.z); o[3] = bfbits(f0.w);
    o[4] = bfbits(f1.x); o[5] = bfbits(f1.y); o[6] = bfbits(f1.z); o[7] = bfbits(f1.w);
    *(short8*)(dst) = o;
}

// ============ fp32 -> bf16 pre-convert (merged: all 5 tensors, 1 dispatch) ============
__global__ __launch_bounds__(256)
void cvt_all(const float* __restrict__ x,  const float* __restrict__ wq,
             const float* __restrict__ wk, const float* __restrict__ wv,
             const float* __restrict__ wo, bf16* __restrict__ dst,
             bf16* __restrict__ wob)
{
    const size_t i = ((size_t)blockIdx.x * 256 + threadIdx.x) * 8;
    if (i < (size_t)OUTN + 3 * WN) {
        const float* src; size_t off;
        if (i < (size_t)OUTN)               { src = x;  off = i; }
        else if (i < (size_t)OUTN + WN)     { src = wq; off = i - OUTN; }
        else if (i < (size_t)OUTN + 2 * WN) { src = wk; off = i - OUTN - WN; }
        else                                { src = wv; off = i - OUTN - 2 * (size_t)WN; }
        cvt8(src + off, dst + i);
    } else {
        const size_t off = i - OUTN - 3 * (size_t)WN;
        cvt8(wo + off, wob + off);
    }
}

// fallback path kernels (ws < 26 MB)
__global__ __launch_bounds__(256)
void cvt_inputs(const float* __restrict__ x,  const float* __restrict__ wq,
                const float* __restrict__ wk, const float* __restrict__ wv,
                bf16* __restrict__ dst)
{
    const size_t i = ((size_t)blockIdx.x * 256 + threadIdx.x) * 8;
    const float* src; size_t off;
    if (i < (size_t)OUTN)               { src = x;  off = i; }
    else if (i < (size_t)OUTN + WN)     { src = wq; off = i - OUTN; }
    else if (i < (size_t)OUTN + 2 * WN) { src = wk; off = i - OUTN - WN; }
    else                                { src = wv; off = i - OUTN - 2 * (size_t)WN; }
    cvt8(src + off, dst + i);
}

__global__ __launch_bounds__(256)
void cvt_wo(const float* __restrict__ wo, bf16* __restrict__ dst)
{
    const size_t i = ((size_t)blockIdx.x * 256 + threadIdx.x) * 8;
    cvt8(wo + i, dst + i);
}

// ============ bf16 MFMA GEMM, fused-z, 512 thr, BK=64 dbuf 2ph (R4-verified) ============
// MODE 0 (NZ=3): A=xb; z0 -> q PRESCALED, z1 -> k, z2 -> V^T packed stores.
// MODE 1 (NZ=1): A=attn-out; output fp32 row-major.
template<int MODE, int NZ>
__global__ __launch_bounds__(512, 2)
void gemm_mfma(const bf16* __restrict__ A,
               const bf16* __restrict__ W0, const bf16* __restrict__ W1,
               const bf16* __restrict__ W2,
               bf16* __restrict__ C0, bf16* __restrict__ C1, bf16* __restrict__ C2,
               float* __restrict__ F)
{
    __shared__ __align__(16) bf16 smem[(1 + NZ) * 8192 * 2];

    const int t    = threadIdx.x;
    const int wave = t >> 6;
    const int lane = t & 63;
    const int quad = lane >> 4;
    const int l16  = lane & 15;
    const int m0 = blockIdx.y * 128;
    const int n0 = blockIdx.x * 128;
    const int wr = (wave >> 2) * 64;     // 2 row-groups
    const int wc = (wave & 3) * 32;      // 4 col-groups

    const bf16* Wp[3] = {W0, W1, W2};

    floatx4 acc[NZ][4][2] = {};

    auto stage = [&](int kt, int bb) {
        bf16* Bb = smem + bb * (1 + NZ) * 8192;
        const int k0 = kt * 64;
        #pragma unroll
        for (int p = 0; p < 2; p++) {
            const int ck = p * 512 + t;            // 1024 chunks per tensor
            const int kr = ck >> 3;
            const int kg = (ck & 7) ^ (kr & 7);
            async16(Bb + ck * 8, A + (size_t)(m0 + kr) * DM + k0 + kg * 8);
            #pragma unroll
            for (int zz = 0; zz < NZ; zz++)
                async16(Bb + (1 + zz) * 8192 + ck * 8,
                        Wp[zz] + (size_t)(n0 + kr) * DM + k0 + kg * 8);
        }
    };

    stage(0, 0);
    __syncthreads();                       // prologue drain: tile 0 resident

    for (int kt = 0; kt < DM / 64; ++kt) {
        const int cur = kt & 1;
        if (kt + 1 < DM / 64) stage(kt + 1, cur ^ 1);   // prefetch BEFORE compute

        const bf16* Bb = smem + cur * (1 + NZ) * 8192;

        #pragma unroll
        for (int ks = 0; ks < 2; ks++) {
            short8 af[4];
            #pragma unroll
            for (int i = 0; i < 4; i++) {
                const int r = wr + i * 16 + l16;
                af[i] = *(const short8*)(Bb + r * 64 + ((ks * 4 + quad) ^ (r & 7)) * 8);
            }
            #pragma unroll
            for (int zz = 0; zz < NZ; zz++) {
                short8 wf[2];
                #pragma unroll
                for (int j = 0; j < 2; j++) {
                    const int n = wc + j * 16 + l16;
                    wf[j] = *(const short8*)(Bb + (1 + zz) * 8192 + n * 64 +
                                             ((ks * 4 + quad) ^ (n & 7)) * 8);
                }
                __builtin_amdgcn_s_setprio(1);
                #pragma unroll
                for (int i = 0; i < 4; i++)
                    #pragma unroll
                    for (int j = 0; j < 2; j++)
                        acc[zz][i][j] = __builtin_amdgcn_mfma_f32_16x16x32_bf16(
                            af[i], wf[j], acc[zz][i][j], 0, 0, 0);
                __builtin_amdgcn_s_setprio(0);
            }
        }
        __syncthreads();   // all waves done with cur; prefetched tile resident
    }

    // ---- epilogue (C/D layout: col=lane&15, row=quad*4+reg [m89/m91]) ----
    #pragma unroll
    for (int zz = 0; zz < NZ; zz++) {
        #pragma unroll
        for (int i = 0; i < 4; i++) {
            #pragma unroll
            for (int j = 0; j < 2; j++) {
                if (MODE == 0 && zz == 2) {
                    // V^T [B,H,DH,S]: r <-> consecutive s -> packed 8B store
                    const int s0 = m0 + wr + i * 16 + quad * 4;
                    const int gn = n0 + wc + j * 16 + l16;
                    const int b = s0 >> 11, sr = s0 & (SEQ - 1);
                    const int h = gn >> 6,  d = gn & (DH - 1);
                    shorts4 pv;
                    #pragma unroll
                    for (int r = 0; r < 4; r++) pv[r] = bfbits(acc[zz][i][j][r]);
                    *(shorts4*)(C2 + (((size_t)(b * NH + h)) * DH + d) * SEQ + sr) = pv;
                } else {
                    #pragma unroll
                    for (int r = 0; r < 4; r++) {
                        const int gm = m0 + wr + i * 16 + quad * 4 + r;
                        const int gn = n0 + wc + j * 16 + l16;
                        if (MODE == 1) {
                            F[(size_t)gm * DM + gn] = acc[zz][i][j][r];    // fp32
                        } else {
                            float av = acc[zz][i][j][r];
                            if (zz == 0) av *= 0.18033688f;  // (1/sqrt(DH))*log2(e)
                            bf16* dst = (zz == 0) ? C0 : C1;
                            dst[(size_t)gm * DM + gn] = __float2bfloat16(av);
                        }
                    }
                }
            }
        }
    }
}

// ============ attn compute tile: FORCEINLINE, accumulators by array-reference ============
__device__ __forceinline__ void attn_tile(const bf16* Ks, int kbase, int qrow,
                                          const short8 (&qf)[4],
                                          floatx16 (&oacc)[2], float& lsum,
                                          int khalf, int hi, int l32)
{
    if (kbase > qrow + 31) return;
    const bf16* Vs = Ks + 8192;
    const int qg = qrow + l32;

    #pragma unroll
    for (int kt = 0; kt < 2; kt++) {
        const int kb = kbase + kt * 32;
        if (kb > qrow + 31) continue;

        // ---- QK^T: S^T[32 keys][32 q] ----
        const int krow = khalf * 64 + kt * 32 + l32;
        floatx16 sc = {};
        #pragma unroll
        for (int sg = 0; sg < 4; sg++) {
            const int g = (sg * 2 + hi) ^ (krow & 7);
            short8 kf = *(const short8*)(Ks + krow * 64 + g * 8);
            sc = __builtin_amdgcn_mfma_f32_32x32x16_bf16(kf, qf[sg], sc, 0, 0, 0);
        }

        // ---- causal mask on diagonal tiles ----
        if (kb + 31 > qrow) {
            #pragma unroll
            for (int r = 0; r < 16; r++) {
                const int key = kb + (r & 3) + 8 * (r >> 2) + 4 * hi;
                sc[r] = (key <= qg) ? sc[r] : -1e30f;
            }
        }

        // ---- p = exp2(s), partial l ----
        #pragma unroll
        for (int r = 0; r < 16; r++) {
            const float p = __builtin_amdgcn_exp2f(sc[r]);
            sc[r] = p;
            lsum += p;
        }

        // ---- pack P pairs: d[g][i] = keys 8g+4hi+2i+{0,1} (q = l32) ----
        unsigned d[4][2];
        #pragma unroll
        for (int g = 0; g < 4; g++) {
            d[g][0] = pack2(sc[4 * g + 0], sc[4 * g + 1]);
            d[g][1] = pack2(sc[4 * g + 2], sc[4 * g + 3]);
        }

        // ---- PV per 16-key segment: one shfl_xor(32) pair builds B-frag ----
        #pragma unroll
        for (int h16 = 0; h16 < 2; h16++) {
            const unsigned a0 = d[h16 * 2][0],     a1 = d[h16 * 2][1];
            const unsigned b0 = d[h16 * 2 + 1][0], b1 = d[h16 * 2 + 1][1];
            const unsigned mine0 = hi ? b0 : a0, mine1 = hi ? b1 : a1;
            const unsigned give0 = hi ? a0 : b0, give1 = hi ? a1 : b1;
            const unsigned r0 = (unsigned)__shfl_xor((int)give0, 32, 64);
            const unsigned r1 = (unsigned)__shfl_xor((int)give1, 32, 64);
            uintx4 pw;
            pw[0] = hi ? r0 : mine0;
            pw[1] = hi ? r1 : mine1;
            pw[2] = hi ? mine0 : r0;
            pw[3] = hi ? mine1 : r1;
            short8 pb = __builtin_bit_cast(short8, pw);

            const int Gbase = khalf * 8 + kt * 4 + h16 * 2 + hi;
            #pragma unroll
            for (int tile = 0; tile < 2; tile++) {
                const int vrow = tile * 32 + l32;
                const int vg = Gbase ^ (vrow & 15);
                short8 vf = *(const short8*)(Vs + vrow * 128 + vg * 8);
                oacc[tile] = __builtin_amdgcn_mfma_f32_32x32x16_bf16(vf, pb, oacc[tile], 0, 0, 0);
            }
        }
    }
}

// ============ MFMA causal flash attention: paired q-tiles + XCD-pinned heads ============
// (R8-verified exact: best measured attn; best total 157.6us.)
// grid (8, NH, BATCH) = 256 blocks (1/CU), 8 waves. Role remap from FLAT id:
// xcd = id&7; each XCD owns 4 (h,b) pairs; the 8 q-tile-pair blocks of a given
// (h,b) share id%8 -> same XCD -> head's K/V L2-resident.
// Block processes causal-complementary pair (qtA, 15-qtA): 17 slots always.
// Triple-buffered 128-key staging, counted s_waitcnt vmcnt(4) + raw s_barrier.
// Q,K row-major [B,S,DM] (q prescaled by 0.125*log2e); V^T [B,H,DH,S].
// 32x32 layouts (m74/m101): C/D col=lane&31, row=(r&3)+8*(r>>2)+4*(lane>>5).
__global__ __launch_bounds__(512, 2)
void attn_flash(bf16* __restrict__ Q, const bf16* __restrict__ K,
                const bf16* __restrict__ Vt)
{
    // 96KB: 3 x (Ks[128][64] g^=row&7 | Vs[64][128] g^=row&15) stage buffers.
    __shared__ __align__(16) bf16 smem[49152];

    const int t    = threadIdx.x;
    const int wave = t >> 6;
    const int lane = t & 63;
    const int hi   = lane >> 5;
    const int l32  = lane & 31;

    // ---- XCD-pinned role remap (bijective on 256 blocks) ----
    const int id  = blockIdx.x + 8 * (blockIdx.y + NH * blockIdx.z);
    const int xcd = id & 7;
    const int jj  = id >> 3;               // 0..31
    const int p   = xcd * 4 + (jj >> 3);   // head-pair index 0..31
    const int h   = p & (NH - 1);
    const int b   = p >> 4;
    const int qtA = jj & 7;                // 0..7
    const int qtB = 15 - qtA;              // 8..15

    const int hc  = h * DH;
    const size_t rowb = (size_t)b * SEQ;
    const size_t bhv  = ((size_t)(b * NH + h)) * SEQ * DH;

    const int qw    = wave & 3;
    const int khalf = wave >> 2;
    const int qrA = qtA * 128 + qw * 32;
    const int qrB = qtB * 128 + qw * 32;

    short8 qfA[4], qfB[4];
    #pragma unroll
    for (int sg = 0; sg < 4; sg++) {
        qfA[sg] = *(const short8*)(Q + (rowb + qrA + l32) * DM + hc + sg * 16 + hi * 8);
        qfB[sg] = *(const short8*)(Q + (rowb + qrB + l32) * DM + hc + sg * 16 + hi * 8);
    }

    floatx16 oaccA[2] = {}, oaccB[2] = {};
    float lsumA = 0.f, lsumB = 0.f;

    constexpr int NSLOT = 17;

    auto slotK0 = [&](int s) { return (s <= qtA ? s : s - qtA - 1) * 128; };

    auto stage = [&](int s) {
        bf16* Kb = smem + (s % 3) * 16384;
        bf16* Vb = Kb + 8192;
        const int k0 = slotK0(s);
        #pragma unroll
        for (int pp = 0; pp < 2; pp++) {
            const int ck = pp * 512 + t;
            const int kr = ck >> 3;
            const int kg = (ck & 7) ^ (kr & 7);
            async16(Kb + ck * 8, K + (rowb + k0 + kr) * DM + hc + kg * 8);
            const int vr = ck >> 4;
            const int vg = (ck & 15) ^ (vr & 15);
            async16(Vb + ck * 8, Vt + bhv + (size_t)vr * SEQ + k0 + vg * 8);
        }
    };

    // ---- pipelined main loop: issue s+2, wait slot s (vmcnt 4), compute s ----
    stage(0);
    stage(1);
    for (int s = 0; s < NSLOT - 1; ++s) {
        asm volatile("s_waitcnt vmcnt(4)" ::: "memory");   // slot s resident (own 4)
        __builtin_amdgcn_s_barrier();                      // all lanes' slot s done
        if (s + 2 < NSLOT) stage(s + 2);
        const bf16* Ks = smem + (s % 3) * 16384;
        if (s <= qtA)
            attn_tile(Ks, s * 128 + khalf * 64, qrA, qfA, oaccA, lsumA, khalf, hi, l32);
        else
            attn_tile(Ks, (s - qtA - 1) * 128 + khalf * 64, qrB, qfB, oaccB, lsumB, khalf, hi, l32);
    }
    asm volatile("s_waitcnt vmcnt(0)" ::: "memory");
    __builtin_amdgcn_s_barrier();
    attn_tile(smem + ((NSLOT - 1) % 3) * 16384,
              (NSLOT - 2 - qtA) * 128 + khalf * 64, qrB, qfB, oaccB, lsumB, khalf, hi, l32);

    // ---- per-wave l: other 16-key half of this wave's range is in lane^32 ----
    lsumA += __shfl_xor(lsumA, 32, 64);
    lsumB += __shfl_xor(lsumB, 32, 64);

    // ---- combine khalf pair via LDS (staging dead now) ----
    __syncthreads();
    float* dmp = (float*)smem;                    // [2][4][32][66] = 16896 f
    float* lP  = dmp + 2 * 4 * 32 * 66;           // [2][4][32]     = 256 f
    if (khalf == 1) {
        #pragma unroll
        for (int m = 0; m < 2; m++) {
            const floatx16* oc = m ? oaccB : oaccA;
            #pragma unroll
            for (int tile = 0; tile < 2; tile++)
                #pragma unroll
                for (int r = 0; r < 16; r++) {
                    const int dd = tile * 32 + (r & 3) + 8 * (r >> 2) + 4 * hi;
                    dmp[((m * 4 + qw) * 32 + l32) * 66 + dd] = oc[tile][r];
                }
            if (!hi) lP[(m * 4 + qw) * 32 + l32] = m ? lsumB : lsumA;
        }
    }
    __syncthreads();

    if (khalf == 0) {
        // slabs after dump region: bf16 index 34304 (= 68608 B), 32x72 per qw
        bf16* T8 = smem + 34304 + qw * 2304;
        #pragma unroll
        for (int m = 0; m < 2; m++) {
            const floatx16* oc = m ? oaccB : oaccA;
            const float lt = (m ? lsumB : lsumA) + lP[(m * 4 + qw) * 32 + l32];
            const float invl = 1.0f / lt;
            const int qrow = m ? qrB : qrA;
            #pragma unroll
            for (int tile = 0; tile < 2; tile++)
                #pragma unroll
                for (int rq = 0; rq < 4; rq++) {
                    shorts4 v4;
                    #pragma unroll
                    for (int sg = 0; sg < 4; sg++) {
                        const int r = rq * 4 + sg;
                        const int dd = tile * 32 + (r & 3) + 8 * (r >> 2) + 4 * hi;
                        const float comb = oc[tile][r] + dmp[((m * 4 + qw) * 32 + l32) * 66 + dd];
                        v4[sg] = bfbits(comb * invl);
                    }
                    *(shorts4*)(T8 + l32 * 72 + tile * 32 + rq * 8 + hi * 4) = v4;
                }
            asm volatile("s_waitcnt lgkmcnt(0)" ::: "memory");  // cross-lane RAW in-wave
            #pragma unroll
            for (int p2 = 0; p2 < 4; p2++) {
                const int rq = (lane >> 3) + p2 * 8;
                const int dd = (lane & 7) * 8;
                short8 v8 = *(const short8*)(T8 + rq * 72 + dd);
                *(short8*)(Q + (rowb + qrow + rq) * DM + hc + dd) = v8;
            }
            asm volatile("s_waitcnt lgkmcnt(0)" ::: "memory");  // drain before slab reuse
        }
    }
}

extern "C" void kernel_launch(void* const* d_in, const int* in_sizes, int n_in,
                              void* d_out, int out_size, void* d_ws, size_t ws_size,
                              hipStream_t stream)
{
    const float* x  = (const float*)d_in[0];
    const float* wq = (const float*)d_in[1];
    const float* wk = (const float*)d_in[2];
    const float* wv = (const float*)d_in[3];
    const float* wo = (const float*)d_in[4];
    float* out = (float*)d_out;

    // ws: q | k | vT bf16 (24 MB) [+ wob 2 MB if ws >= 26 MB]
    bf16* qb = (bf16*)d_ws;
    bf16* kb = qb + (size_t)OUTN;
    bf16* vb = kb + (size_t)OUTN;

    // d_out doubles as bf16 scratch until the final GEMM overwrites it
    bf16* xb  = (bf16*)d_out;
    bf16* wqb = xb + (size_t)OUTN;
    bf16* wkb = wqb + WN;
    bf16* wvb = wkb + WN;

    const bool wsBig = ws_size >= (size_t)(3 * (size_t)OUTN + WN) * sizeof(bf16); // 26 MB

    if (wsBig) {
        bf16* wob = vb + (size_t)OUTN;     // ws+24MB, untouched by qkv/attn
        cvt_all<<<(OUTN + 4 * WN) / (8 * 256), 256, 0, stream>>>(
            x, wq, wk, wv, wo, xb, wob);
        gemm_mfma<0, 3><<<dim3(DM / 128, MROWS / 128), dim3(512), 0, stream>>>(
            xb, wqb, wkb, wvb, qb, kb, vb, nullptr);
        attn_flash<<<dim3(8, NH, BATCH), dim3(512), 0, stream>>>(qb, kb, vb);
        gemm_mfma<1, 1><<<dim3(DM / 128, MROWS / 128), dim3(512), 0, stream>>>(
            qb, wob, nullptr, nullptr, nullptr, nullptr, nullptr, out);
    } else {
        cvt_inputs<<<(OUTN + 3 * WN) / (8 * 256), 256, 0, stream>>>(x, wq, wk, wv, xb);
        gemm_mfma<0, 3><<<dim3(DM / 128, MROWS / 128), dim3(512), 0, stream>>>(
            xb, wqb, wkb, wvb, qb, kb, vb, nullptr);
        attn_flash<<<dim3(8, NH, BATCH), dim3(512), 0, stream>>>(qb, kb, vb);
        bf16* wob = kb;    // kb dead after attention
        cvt_wo<<<WN / (8 * 256), 256, 0, stream>>>(wo, wob);
        gemm_mfma<1, 1><<<dim3(DM / 128, MROWS / 128), dim3(512), 0, stream>>>(
            qb, wob, nullptr, nullptr, nullptr, nullptr, nullptr, out);
    }
}